// Round 17
// baseline (108.943 us; speedup 1.0000x reference)
//
#include <hip/hip_runtime.h>

// Maj3: out[b,o,h,w] = sum_{kh,c} sign( sum_{kw} x[b,c,h+kh-1,w+kw-1] * W[o,kw,kh,c] )
// x: (4,64,56,56) f32; W: (64,3,3,64) f32; out: (4,64,56,56) f32.
// Bit-exactness vs numpy required (threshold 1.36, integer output): contract(off),
// reference mul/add order per sign. Padded rows staged as 0.0 -> sums are +-0;
// the (s < 0) predicate counts neither, and base=nvalid*64 excludes them.
//
// R17: R16's OG=8 spilled again (261MB scratch writes; 72 weight VGPRs across
// 112 unrolled asm blocks fragment live ranges — same law as R10: ~36 weight
// regs/wave is the allocator's ceiling). Revert to R15's proven per-wave shape
// (28px x 4o x 36 wreg) and fix ONLY grid balance: 256-thr blocks (4 waves =
// 4 o-groups), grid (224,2,4) = 1792 = exactly 7 blocks/CU (R15: 896 = 3.5/CU,
// ~14% round imbalance). LDS 23.8KB -> 6 resident (24 waves/CU), 7th backfills.

#define Cn 64
#define Hn 56
#define Wn 56
#define On 64
#define OG 4        // output channels per wave (proven spill-free budget)
#define PIX 28      // pixels per wave (half row)
#define SLABW 30    // staged taps per row: w0-1 .. w0+28
#define SLABP 31    // padded stride (odd -> 2 lanes/bank = conflict-free)

// v_writelane_b32: write wave-uniform `val` into lane `LANE` of `dst`.
// (No writelane builtin on this toolchain — inline asm, non-volatile so the
// scheduler may move it freely; value-tied via "+v".)
#define WRITELANE(dst, val, LANE)                                             \
    asm("v_writelane_b32 %0, %1, " #LANE                                      \
        : "+v"(dst) : "s"(val))

__global__ __launch_bounds__(256, 6)
void maj3_kernel(const float* __restrict__ x,
                 const float* __restrict__ wt,
                 float* __restrict__ out)
{
#pragma clang fp contract(off)
    __shared__ float slab[3][Cn][SLABP];

    const int lane  = threadIdx.x & 63;   // = channel c
    const int wave  = __builtin_amdgcn_readfirstlane((int)(threadIdx.x >> 6)); // 0..3
    const int bh    = blockIdx.x;         // 0..223
    const int b     = bh / Hn;
    const int h     = bh - b * Hn;
    const int w0    = blockIdx.y * PIX;   // 0 or 28
    const int obase = blockIdx.z * 16 + wave * OG;   // this wave's o range

    // Stage x[b, :, h-1..h+1, w0-1..w0+28] into slab; pads (rows and cols)
    // staged as exact 0.0f. 5760 elements over 256 threads, once per block.
    const float* xb = x + b * (Cn * Hn * Wn);
    for (int i = threadIdx.x; i < 3 * Cn * SLABW; i += 256) {
        const int ws  = i % SLABW;
        const int t   = i / SLABW;
        const int c   = t & (Cn - 1);
        const int r   = t >> 6;
        const int row = h + r - 1;
        const int w   = w0 - 1 + ws;
        float v = 0.0f;
        if (row >= 0 && row < Hn && (unsigned)w < (unsigned)Wn)
            v = xb[(c * Hn + row) * Wn + w];
        slab[r][c][ws] = v;
    }

    // This wave's weights, lane = c: W[o,kw,kh,c] = wt[((o*3+kw)*3+kh)*64+c].
    // 36 coalesced 256B loads, once; lives in 36 VGPRs for the whole kernel.
    float wreg[OG][3][3];
    #pragma unroll
    for (int oo = 0; oo < OG; ++oo)
        #pragma unroll
        for (int kw = 0; kw < 3; ++kw)
            #pragma unroll
            for (int kh = 0; kh < 3; ++kh)
                wreg[oo][kh][kw] = wt[(((obase + oo) * 3 + kw) * 3 + kh) * Cn + lane];

    __syncthreads();

    int vcnt[OG];                         // lane p holds neg-count for pixel p
    #pragma unroll
    for (int oo = 0; oo < OG; ++oo) vcnt[oo] = 0;

    // Sliding 3-tap windows, one per kh row (pure SSA renames under unroll).
    float xl[3], xm[3];
    #pragma unroll
    for (int r = 0; r < 3; ++r) {
        xl[r] = slab[r][lane][0];
        xm[r] = slab[r][lane][1];
    }

#define PBODY(P)                                                              \
    do {                                                                      \
        float xr[3];                                                          \
        _Pragma("unroll")                                                     \
        for (int r = 0; r < 3; ++r) xr[r] = slab[r][lane][(P) + 2];           \
        _Pragma("unroll")                                                     \
        for (int oo = 0; oo < OG; ++oo) {                                     \
            int cnt = 0;                                                      \
            _Pragma("unroll")                                                 \
            for (int r = 0; r < 3; ++r) {                                     \
                const float s = (xl[r] * wreg[oo][r][0] +                     \
                                 xm[r] * wreg[oo][r][1])                      \
                              + xr[r] * wreg[oo][r][2];                       \
                cnt += (int)__popcll(__ballot(s < 0.0f));                     \
            }                                                                 \
            const int cs = __builtin_amdgcn_readfirstlane(cnt);              \
            WRITELANE(vcnt[oo], cs, P);                                       \
        }                                                                     \
        _Pragma("unroll")                                                     \
        for (int r = 0; r < 3; ++r) { xl[r] = xm[r]; xm[r] = xr[r]; }         \
    } while (0)

    PBODY(0);  PBODY(1);  PBODY(2);  PBODY(3);  PBODY(4);  PBODY(5);
    PBODY(6);  PBODY(7);  PBODY(8);  PBODY(9);  PBODY(10); PBODY(11);
    PBODY(12); PBODY(13); PBODY(14); PBODY(15); PBODY(16); PBODY(17);
    PBODY(18); PBODY(19); PBODY(20); PBODY(21); PBODY(22); PBODY(23);
    PBODY(24); PBODY(25); PBODY(26); PBODY(27);

    // out = nvalid*64 - 2*negcount (padded rows excluded; their staged-zero
    // sums are +-0 -> (s<0) false -> never counted).
    const int nvalid = 3 - (h == 0) - (h == Hn - 1);
    const float base = (float)(nvalid * Cn);
    if (lane < PIX) {
        float* ob = out + ((b * On + obase) * Hn + h) * Wn + w0 + lane;
        #pragma unroll
        for (int oo = 0; oo < OG; ++oo)
            ob[oo * Hn * Wn] = base - 2.0f * (float)vcnt[oo];
    }
}

extern "C" void kernel_launch(void* const* d_in, const int* in_sizes, int n_in,
                              void* d_out, int out_size, void* d_ws, size_t ws_size,
                              hipStream_t stream) {
    const float* x  = (const float*)d_in[0];
    const float* wt = (const float*)d_in[1];
    float* o        = (float*)d_out;
    dim3 grid(224, 2, 4);   // (b,h) x w-half x o-quarter; 4 waves x (28px, 4o)
    maj3_kernel<<<grid, dim3(256), 0, stream>>>(x, wt, o);
}

// Round 18
// 32.758 us; speedup vs baseline: 3.3257x; 3.3257x over previous
//
#include <hip/hip_runtime.h>

// Maj3: out[b,o,h,w] = sum_{kh,c} sign( sum_{kw} x[b,c,h+kh-1,w+kw-1] * W[o,kw,kh,c] )
// x: (4,64,56,56) f32; W: (64,3,3,64) f32; out: (4,64,56,56) f32.
// Bit-exactness vs numpy required (threshold 1.36, integer output): contract(off),
// reference mul/add order per sign. Padded rows staged as 0.0 -> sums are +-0;
// the (s < 0) predicate counts neither, and base=nvalid*64 excludes them.
//
// R18: R17's spill isolated to the launch-bounds cap: identical code shape was
// clean at cap-128 (R15, (512,4)) and spilled at cap-85 ((256,6) -> 139MB
// fetch / 217MB write scratch traffic). ONE change: __launch_bounds__(256,4)
// -> 128-VGPR cap. Keeps R17's perfect grid balance (1792 blocks = 7/CU;
// LDS 23.8KB -> 6 resident, 7th backfills at ~4us granularity).

#define Cn 64
#define Hn 56
#define Wn 56
#define On 64
#define OG 4        // output channels per wave (proven spill-free budget)
#define PIX 28      // pixels per wave (half row)
#define SLABW 30    // staged taps per row: w0-1 .. w0+28
#define SLABP 31    // padded stride (odd -> 2 lanes/bank = conflict-free)

// v_writelane_b32: write wave-uniform `val` into lane `LANE` of `dst`.
// (No writelane builtin on this toolchain — inline asm, non-volatile so the
// scheduler may move it freely; value-tied via "+v".)
#define WRITELANE(dst, val, LANE)                                             \
    asm("v_writelane_b32 %0, %1, " #LANE                                      \
        : "+v"(dst) : "s"(val))

__global__ __launch_bounds__(256, 4)
void maj3_kernel(const float* __restrict__ x,
                 const float* __restrict__ wt,
                 float* __restrict__ out)
{
#pragma clang fp contract(off)
    __shared__ float slab[3][Cn][SLABP];

    const int lane  = threadIdx.x & 63;   // = channel c
    const int wave  = __builtin_amdgcn_readfirstlane((int)(threadIdx.x >> 6)); // 0..3
    const int bh    = blockIdx.x;         // 0..223
    const int b     = bh / Hn;
    const int h     = bh - b * Hn;
    const int w0    = blockIdx.y * PIX;   // 0 or 28
    const int obase = blockIdx.z * 16 + wave * OG;   // this wave's o range

    // Stage x[b, :, h-1..h+1, w0-1..w0+28] into slab; pads (rows and cols)
    // staged as exact 0.0f. 5760 elements over 256 threads, once per block.
    const float* xb = x + b * (Cn * Hn * Wn);
    for (int i = threadIdx.x; i < 3 * Cn * SLABW; i += 256) {
        const int ws  = i % SLABW;
        const int t   = i / SLABW;
        const int c   = t & (Cn - 1);
        const int r   = t >> 6;
        const int row = h + r - 1;
        const int w   = w0 - 1 + ws;
        float v = 0.0f;
        if (row >= 0 && row < Hn && (unsigned)w < (unsigned)Wn)
            v = xb[(c * Hn + row) * Wn + w];
        slab[r][c][ws] = v;
    }

    // This wave's weights, lane = c: W[o,kw,kh,c] = wt[((o*3+kw)*3+kh)*64+c].
    // 36 coalesced 256B loads, once; lives in 36 VGPRs for the whole kernel.
    float wreg[OG][3][3];
    #pragma unroll
    for (int oo = 0; oo < OG; ++oo)
        #pragma unroll
        for (int kw = 0; kw < 3; ++kw)
            #pragma unroll
            for (int kh = 0; kh < 3; ++kh)
                wreg[oo][kh][kw] = wt[(((obase + oo) * 3 + kw) * 3 + kh) * Cn + lane];

    __syncthreads();

    int vcnt[OG];                         // lane p holds neg-count for pixel p
    #pragma unroll
    for (int oo = 0; oo < OG; ++oo) vcnt[oo] = 0;

    // Sliding 3-tap windows, one per kh row (pure SSA renames under unroll).
    float xl[3], xm[3];
    #pragma unroll
    for (int r = 0; r < 3; ++r) {
        xl[r] = slab[r][lane][0];
        xm[r] = slab[r][lane][1];
    }

#define PBODY(P)                                                              \
    do {                                                                      \
        float xr[3];                                                          \
        _Pragma("unroll")                                                     \
        for (int r = 0; r < 3; ++r) xr[r] = slab[r][lane][(P) + 2];           \
        _Pragma("unroll")                                                     \
        for (int oo = 0; oo < OG; ++oo) {                                     \
            int cnt = 0;                                                      \
            _Pragma("unroll")                                                 \
            for (int r = 0; r < 3; ++r) {                                     \
                const float s = (xl[r] * wreg[oo][r][0] +                     \
                                 xm[r] * wreg[oo][r][1])                      \
                              + xr[r] * wreg[oo][r][2];                       \
                cnt += (int)__popcll(__ballot(s < 0.0f));                     \
            }                                                                 \
            const int cs = __builtin_amdgcn_readfirstlane(cnt);              \
            WRITELANE(vcnt[oo], cs, P);                                       \
        }                                                                     \
        _Pragma("unroll")                                                     \
        for (int r = 0; r < 3; ++r) { xl[r] = xm[r]; xm[r] = xr[r]; }         \
    } while (0)

    PBODY(0);  PBODY(1);  PBODY(2);  PBODY(3);  PBODY(4);  PBODY(5);
    PBODY(6);  PBODY(7);  PBODY(8);  PBODY(9);  PBODY(10); PBODY(11);
    PBODY(12); PBODY(13); PBODY(14); PBODY(15); PBODY(16); PBODY(17);
    PBODY(18); PBODY(19); PBODY(20); PBODY(21); PBODY(22); PBODY(23);
    PBODY(24); PBODY(25); PBODY(26); PBODY(27);

    // out = nvalid*64 - 2*negcount (padded rows excluded; their staged-zero
    // sums are +-0 -> (s<0) false -> never counted).
    const int nvalid = 3 - (h == 0) - (h == Hn - 1);
    const float base = (float)(nvalid * Cn);
    if (lane < PIX) {
        float* ob = out + ((b * On + obase) * Hn + h) * Wn + w0 + lane;
        #pragma unroll
        for (int oo = 0; oo < OG; ++oo)
            ob[oo * Hn * Wn] = base - 2.0f * (float)vcnt[oo];
    }
}

extern "C" void kernel_launch(void* const* d_in, const int* in_sizes, int n_in,
                              void* d_out, int out_size, void* d_ws, size_t ws_size,
                              hipStream_t stream) {
    const float* x  = (const float*)d_in[0];
    const float* wt = (const float*)d_in[1];
    float* o        = (float*)d_out;
    dim3 grid(224, 2, 4);   // (b,h) x w-half x o-quarter; 4 waves x (28px, 4o)
    maj3_kernel<<<grid, dim3(256), 0, stream>>>(x, wt, o);
}

// Round 19
// 30.528 us; speedup vs baseline: 3.5686x; 1.0730x over previous
//
#include <hip/hip_runtime.h>

// Maj3: out[b,o,h,w] = sum_{kh,c} sign( sum_{kw} x[b,c,h+kh-1,w+kw-1] * W[o,kw,kh,c] )
// x: (4,64,56,56) f32; W: (64,3,3,64) f32; out: (4,64,56,56) f32.
// Bit-exactness vs numpy required (threshold 1.36, integer output): contract(off),
// reference mul/add order per sign. Padded rows staged as 0.0 -> sums are +-0;
// the (s < 0) predicate counts neither, and base=nvalid*64 excludes them.
//
// R19: R15/R18 tie at ~32.5us regardless of occupancy/balance -> issue-volume
// bound. Suspect: HIP __ballot(int pred) materializes the bool (v_cmp +
// v_cndmask) then re-ballots it (v_cmp_ne_u32) = 3 VALU per "ballot" instead
// of 1, +672 VALU/wave (+30%). Fix: emit the ballot as ONE v_cmp_lt_f32 into
// an SGPR pair via inline asm (VOP3, inline-0 src1, exec=all-lanes in the
// uniform main loop); popcount via s_bcnt1_b64 on the scalar pipe. All else
// identical to R18 (proven spill-free, balanced 1792 blocks = 7/CU).

#define Cn 64
#define Hn 56
#define Wn 56
#define On 64
#define OG 4        // output channels per wave (proven spill-free budget)
#define PIX 28      // pixels per wave (half row)
#define SLABW 30    // staged taps per row: w0-1 .. w0+28
#define SLABP 31    // padded stride (odd -> 2 lanes/bank = conflict-free)

// v_writelane_b32: write wave-uniform `val` into lane `LANE` of `dst`.
#define WRITELANE(dst, val, LANE)                                             \
    asm("v_writelane_b32 %0, %1, " #LANE                                      \
        : "+v"(dst) : "s"(val))

// One-instruction ballot: mask[lane] = (v < 0.0f). VOP3 v_cmp with explicit
// SGPR-pair dest, inline-constant 0 in src1. Non-volatile -> schedulable.
#define BALLOT_LT0(mask, v)                                                   \
    asm("v_cmp_lt_f32 %0, %1, 0" : "=s"(mask) : "v"(v))

__global__ __launch_bounds__(256, 4)
void maj3_kernel(const float* __restrict__ x,
                 const float* __restrict__ wt,
                 float* __restrict__ out)
{
#pragma clang fp contract(off)
    __shared__ float slab[3][Cn][SLABP];

    const int lane  = threadIdx.x & 63;   // = channel c
    const int wave  = __builtin_amdgcn_readfirstlane((int)(threadIdx.x >> 6)); // 0..3
    const int bh    = blockIdx.x;         // 0..223
    const int b     = bh / Hn;
    const int h     = bh - b * Hn;
    const int w0    = blockIdx.y * PIX;   // 0 or 28
    const int obase = blockIdx.z * 16 + wave * OG;   // this wave's o range

    // Stage x[b, :, h-1..h+1, w0-1..w0+28] into slab; pads (rows and cols)
    // staged as exact 0.0f. 5760 elements over 256 threads, once per block.
    const float* xb = x + b * (Cn * Hn * Wn);
    for (int i = threadIdx.x; i < 3 * Cn * SLABW; i += 256) {
        const int ws  = i % SLABW;
        const int t   = i / SLABW;
        const int c   = t & (Cn - 1);
        const int r   = t >> 6;
        const int row = h + r - 1;
        const int w   = w0 - 1 + ws;
        float v = 0.0f;
        if (row >= 0 && row < Hn && (unsigned)w < (unsigned)Wn)
            v = xb[(c * Hn + row) * Wn + w];
        slab[r][c][ws] = v;
    }

    // This wave's weights, lane = c: W[o,kw,kh,c] = wt[((o*3+kw)*3+kh)*64+c].
    // 36 coalesced 256B loads, once; lives in 36 VGPRs for the whole kernel.
    float wreg[OG][3][3];
    #pragma unroll
    for (int oo = 0; oo < OG; ++oo)
        #pragma unroll
        for (int kw = 0; kw < 3; ++kw)
            #pragma unroll
            for (int kh = 0; kh < 3; ++kh)
                wreg[oo][kh][kw] = wt[(((obase + oo) * 3 + kw) * 3 + kh) * Cn + lane];

    __syncthreads();

    int vcnt[OG];                         // lane p holds neg-count for pixel p
    #pragma unroll
    for (int oo = 0; oo < OG; ++oo) vcnt[oo] = 0;

    // Sliding 3-tap windows, one per kh row (pure SSA renames under unroll).
    float xl[3], xm[3];
    #pragma unroll
    for (int r = 0; r < 3; ++r) {
        xl[r] = slab[r][lane][0];
        xm[r] = slab[r][lane][1];
    }

#define PBODY(P)                                                              \
    do {                                                                      \
        float xr[3];                                                          \
        _Pragma("unroll")                                                     \
        for (int r = 0; r < 3; ++r) xr[r] = slab[r][lane][(P) + 2];           \
        _Pragma("unroll")                                                     \
        for (int oo = 0; oo < OG; ++oo) {                                     \
            int cnt = 0;                                                      \
            _Pragma("unroll")                                                 \
            for (int r = 0; r < 3; ++r) {                                     \
                const float s = (xl[r] * wreg[oo][r][0] +                     \
                                 xm[r] * wreg[oo][r][1])                      \
                              + xr[r] * wreg[oo][r][2];                       \
                unsigned long long m;                                         \
                BALLOT_LT0(m, s);                                             \
                cnt += (int)__builtin_popcountll(m);                          \
            }                                                                 \
            const int cs = __builtin_amdgcn_readfirstlane(cnt);              \
            WRITELANE(vcnt[oo], cs, P);                                       \
        }                                                                     \
        _Pragma("unroll")                                                     \
        for (int r = 0; r < 3; ++r) { xl[r] = xm[r]; xm[r] = xr[r]; }         \
    } while (0)

    PBODY(0);  PBODY(1);  PBODY(2);  PBODY(3);  PBODY(4);  PBODY(5);
    PBODY(6);  PBODY(7);  PBODY(8);  PBODY(9);  PBODY(10); PBODY(11);
    PBODY(12); PBODY(13); PBODY(14); PBODY(15); PBODY(16); PBODY(17);
    PBODY(18); PBODY(19); PBODY(20); PBODY(21); PBODY(22); PBODY(23);
    PBODY(24); PBODY(25); PBODY(26); PBODY(27);

    // out = nvalid*64 - 2*negcount (padded rows excluded; their staged-zero
    // sums are +-0 -> (s<0) false -> never counted).
    const int nvalid = 3 - (h == 0) - (h == Hn - 1);
    const float base = (float)(nvalid * Cn);
    if (lane < PIX) {
        float* ob = out + ((b * On + obase) * Hn + h) * Wn + w0 + lane;
        #pragma unroll
        for (int oo = 0; oo < OG; ++oo)
            ob[oo * Hn * Wn] = base - 2.0f * (float)vcnt[oo];
    }
}

extern "C" void kernel_launch(void* const* d_in, const int* in_sizes, int n_in,
                              void* d_out, int out_size, void* d_ws, size_t ws_size,
                              hipStream_t stream) {
    const float* x  = (const float*)d_in[0];
    const float* wt = (const float*)d_in[1];
    float* o        = (float*)d_out;
    dim3 grid(224, 2, 4);   // (b,h) x w-half x o-quarter; 4 waves x (28px, 4o)
    maj3_kernel<<<grid, dim3(256), 0, stream>>>(x, wt, o);
}